// Round 26
// baseline (30.335 us; speedup 1.0000x reference)
//
#include <hip/hip_runtime.h>
#include <hip/hip_bf16.h>

typedef __attribute__((ext_vector_type(8))) short bf16x8;
typedef __attribute__((ext_vector_type(4))) unsigned short u16x4;
typedef __attribute__((ext_vector_type(4))) float f32x4;
typedef __attribute__((ext_vector_type(2))) float f32x2;

#define NEG_INF (-__builtin_inff())
#define QSCALE (0.125f * 1.4426950408889634f)   // 1/sqrt(64) * log2(e); exp2 domain
#define CONST_M 12.0f                            // safe upper bound on exp2-domain scores
#define NC 4
#define NCL2 2

// K-region LDS swizzle: rows of 128B; spread 16B slots by (row&3)|((row>>3)&1)<<2
#define SWZK(a) ((a) ^ ((((((a) >> 7) & 3) | ((((a) >> 10) & 1) << 2)) << 4)))

static __device__ __forceinline__ unsigned short f2bf(float x) {
  union { float f; unsigned u; } v; v.f = x;
  unsigned r = (v.u + 0x7fffu + ((v.u >> 16) & 1u)) >> 16;
  return (unsigned short)r;
}
static __device__ __forceinline__ float bf2f(unsigned short h) {
  union { unsigned u; float f; } v; v.u = ((unsigned)h) << 16;
  return v.f;
}

// ---- prep: per block, 16 KV rows -> bf16 row-major + blocked transpose
// ---- kvt[blk32][64][32], AND 16 Q rows -> bf16 with QSCALE folded; nt stores ----
__global__ __launch_bounds__(256) void prep_kv_kernel(
    const float* __restrict__ kv, const float* __restrict__ qf,
    const int* __restrict__ kvc,
    unsigned short* __restrict__ kvb, unsigned short* __restrict__ kvt,
    unsigned short* __restrict__ qb,
    int* __restrict__ seg, int nkv, int nq) {
  __shared__ unsigned short tile[16][64];
  const int nb8 = gridDim.x >> 3;
  const int bp = ((gridDim.x & 7) == 0) ? ((blockIdx.x & 7) * nb8 + (blockIdx.x >> 3))
                                        : blockIdx.x;
  const int rowbase = bp * 16;
  const int t = threadIdx.x;
  if (t < 16) {
    int i = rowbase + t;
    if (i < nkv) {
      int c = kvc[i];
      int cp = (i == 0) ? -1 : kvc[i - 1];
      if (c != cp) {
        for (int b = cp + 1; b <= c; ++b) seg[b] = i;
        if (i == 0) for (int b = 0; b < c; ++b) seg[8 + b] = 0;
      }
      int cn = (i == nkv - 1) ? 8 : kvc[i + 1];
      if (c != cn) {
        for (int b = c; b < cn; ++b) seg[8 + b] = i + 1;
        if (i == nkv - 1) for (int b = c + 1; b < 8; ++b) seg[b] = nkv;
      }
    }
  }
  const int r = t >> 4;
  const int c = (t & 15) * 4;
  // Q conversion (scale folded; bit-identical to prior in-attn f2bf(x*QSCALE))
  if (rowbase + r < nq) {
    float4 aq = *(const float4*)(qf + (size_t)(rowbase + r) * 64 + c);
    u16x4 q4;
    q4[0] = f2bf(aq.x * QSCALE); q4[1] = f2bf(aq.y * QSCALE);
    q4[2] = f2bf(aq.z * QSCALE); q4[3] = f2bf(aq.w * QSCALE);
    __builtin_nontemporal_store(q4, (u16x4*)(qb + (size_t)(rowbase + r) * 64 + c));
  }
  float4 a = *(const float4*)(kv + (size_t)(rowbase + r) * 64 + c);
  u16x4 v4;
  v4[0] = f2bf(a.x); v4[1] = f2bf(a.y); v4[2] = f2bf(a.z); v4[3] = f2bf(a.w);
  __builtin_nontemporal_store(v4, (u16x4*)(kvb + (size_t)(rowbase + r) * 64 + c));
  *(u16x4*)&tile[r][c] = v4;
  __syncthreads();
  const int d = t & 63;
  const int k0 = (t >> 6) * 4;
  u16x4 wv;
#pragma unroll
  for (int j = 0; j < 4; ++j) wv[j] = tile[k0 + j][d];
  const int blk = rowbase >> 5;
  const int kbase = (rowbase & 31) + k0;
  __builtin_nontemporal_store(wv, (u16x4*)(kvt + (size_t)blk * 2048 + d * 32 + kbase));
}

// issue the global load for a 32-row KV block (each thread one 16B chunk)
#define STAGE_LOAD(kvx)                                                        \
  {                                                                            \
    const int kvL_ = (kvx);                                                    \
    const char* src_ = stK ? ((const char*)kvb + (size_t)kvL_ * 128 + soff)    \
                           : ((const char*)kvt + (((size_t)kvL_) >> 5) * 4096 + soff); \
    sreg = *(const f32x4*)src_;                                                \
  }
#define STAGE_WRITE(BUF) { *(f32x4*)(ldsbuf[BUF] + doff) = sreg; }

// one 32-kv-row step for this wave's 16 queries, K/V fragments read from LDS
#define STEP(BUF, kvx)                                                         \
  {                                                                            \
    const int kv0_ = (kvx);                                                    \
    const char* Lb_ = ldsbuf[BUF];                                             \
    bf16x8 kf0_ = *(const bf16x8*)(Lb_ + koff0);                               \
    bf16x8 kf1_ = *(const bf16x8*)(Lb_ + koff1);                               \
    bf16x8 kf2_ = *(const bf16x8*)(Lb_ + koff2);                               \
    bf16x8 kf3_ = *(const bf16x8*)(Lb_ + koff3);                               \
    bf16x8 vf0_ = *(const bf16x8*)(Lb_ + voff0);                               \
    bf16x8 vf1_ = *(const bf16x8*)(Lb_ + voff1);                               \
    bf16x8 vf2_ = *(const bf16x8*)(Lb_ + voff2);                               \
    bf16x8 vf3_ = *(const bf16x8*)(Lb_ + voff3);                               \
    f32x4 z_ = {0, 0, 0, 0};                                                   \
    __builtin_amdgcn_s_setprio(1);                                             \
    f32x4 sT0 = __builtin_amdgcn_mfma_f32_16x16x32_bf16(kf0_, qf0, z_, 0, 0, 0); \
    sT0 = __builtin_amdgcn_mfma_f32_16x16x32_bf16(kf1_, qf1, sT0, 0, 0, 0);    \
    f32x4 sT1 = __builtin_amdgcn_mfma_f32_16x16x32_bf16(kf2_, qf0, z_, 0, 0, 0); \
    sT1 = __builtin_amdgcn_mfma_f32_16x16x32_bf16(kf3_, qf1, sT1, 0, 0, 0);    \
    __builtin_amdgcn_s_setprio(0);                                             \
    float v_[8];                                                               \
    const bool full_ = uniformb && (kv0_ >= kv_lo) && (kv0_ + 32 <= kv_hi);    \
    if (full_) {                                                               \
      _Pragma("unroll") for (int r = 0; r < 4; ++r) {                          \
        v_[r] = sT0[r]; v_[4 + r] = sT1[r];                                    \
      }                                                                        \
    } else {                                                                   \
      const int kb0_ = kv0_ + g8;                                              \
      _Pragma("unroll") for (int r = 0; r < 4; ++r) {                          \
        v_[r]     = (kb0_ + r     >= lo_q && kb0_ + r     < hi_q) ? sT0[r] : NEG_INF; \
        v_[4 + r] = (kb0_ + r + 4 >= lo_q && kb0_ + r + 4 < hi_q) ? sT1[r] : NEG_INF; \
      }                                                                        \
    }                                                                          \
    float t_ = fmaxf(fmaxf(fmaxf(v_[0], v_[1]), fmaxf(v_[2], v_[3])),          \
                     fmaxf(fmaxf(v_[4], v_[5]), fmaxf(v_[6], v_[7])));         \
    if (__builtin_expect(__any(t_ > m), 0)) {                                  \
      float tt_ = fmaxf(t_, __shfl_xor(t_, 16));                               \
      tt_ = fmaxf(tt_, __shfl_xor(tt_, 32));                                   \
      float mn_ = fmaxf(m, tt_);                                               \
      float f_ = __builtin_exp2f(m - mn_);                                     \
      l *= f_;                                                                 \
      _Pragma("unroll") for (int r = 0; r < 4; ++r) {                          \
        acc0[r] *= f_; acc1[r] *= f_; acc2[r] *= f_; acc3[r] *= f_;            \
      }                                                                        \
      m = mn_;                                                                 \
    }                                                                          \
    float e_[8];                                                               \
    _Pragma("unroll") for (int i = 0; i < 8; ++i)                              \
      e_[i] = __builtin_exp2f(v_[i] - m);                                      \
    l += (((e_[0] + e_[1]) + (e_[2] + e_[3])) +                                \
          ((e_[4] + e_[5]) + (e_[6] + e_[7])));                                \
    bf16x8 pa_;                                                                \
    _Pragma("unroll") for (int j = 0; j < 8; ++j) pa_[j] = (short)f2bf(e_[j]); \
    __builtin_amdgcn_s_setprio(1);                                             \
    acc0 = __builtin_amdgcn_mfma_f32_16x16x32_bf16(vf0_, pa_, acc0, 0, 0, 0);  \
    acc1 = __builtin_amdgcn_mfma_f32_16x16x32_bf16(vf1_, pa_, acc1, 0, 0, 0);  \
    acc2 = __builtin_amdgcn_mfma_f32_16x16x32_bf16(vf2_, pa_, acc2, 0, 0, 0);  \
    acc3 = __builtin_amdgcn_mfma_f32_16x16x32_bf16(vf3_, pa_, acc3, 0, 0, 0);  \
    __builtin_amdgcn_s_setprio(0);                                             \
  }

// ---- attn partials: 512-thread block = 128 queries (8 waves x 16q), KV block
// ---- staged ONCE into LDS, shared by all 8 waves; KV split NC=4 across blocks
// ---- (halved cold kv/pacc traffic vs NC=8); bf16+nt partials ----
__global__ __launch_bounds__(512, 4) void attn_kernel(
    const unsigned short* __restrict__ qb,   // [n1][64] bf16 (pre-scaled)
    const unsigned short* __restrict__ kvb,  // [n2][64] bf16
    const unsigned short* __restrict__ kvt,  // [n2/32][64][32] bf16
    const int* __restrict__ qc,
    const int* __restrict__ seg,
    unsigned short* __restrict__ pacc,       // [n1][NC][64] bf16
    float* __restrict__ pml,                 // [n1][NC] {m,l} pairs (flat f32)
    int n2)
{
  __shared__ __attribute__((aligned(16))) char ldsbuf[2][8192];  // [K 4KB swz | V 4KB]

  const int per8 = gridDim.x >> 3;
  const int ii = ((gridDim.x & 7) == 0) ? ((blockIdx.x & 7) * per8 + (blockIdx.x >> 3))
                                        : blockIdx.x;
  const int qt = ii >> NCL2;                // 128-query tile
  const int c  = ii & (NC - 1);             // kv chunk
  const int qbase = qt << 7;

  const int tid = threadIdx.x;
  const int w = tid >> 6;                   // 0..7
  const int lane = tid & 63;
  const int q16 = lane & 15;
  const int g = lane >> 4;
  const int g8 = g * 8;
  const int q0w = qbase + w * 16;

  // staging assignment: threads 0-255 stage K rows, 256-511 stage V (kvt block)
  const bool stK = tid < 256;
  const int soff = (tid & 255) * 16;
  const int doff = stK ? SWZK(soff) : 4096 + soff;
  f32x4 sreg;

  const int myb = qc[q0w + q16];
  const int lo_q = seg[myb];
  const int hi_q = seg[8 + myb];
  const int bfirst = qc[qbase];
  const int blast  = qc[qbase + 127];
  const int kv_lo  = seg[bfirst];
  const int kv_hi  = seg[8 + blast];
  const bool uniformb = (bfirst == blast);

  // Q B-fragments (pre-scaled bf16): B[feat=8g+j][q=q16]
  const unsigned short* qr = qb + (size_t)(q0w + q16) * 64 + g8;
  bf16x8 qf0 = *(const bf16x8*)(qr);
  bf16x8 qf1 = *(const bf16x8*)(qr + 32);

  const int base = kv_lo & ~31;
  const int nblk = (kv_hi - base + 31) >> 5;
  const int b0i = (nblk * c) >> NCL2;
  const int b1i = (nblk * (c + 1)) >> NCL2;

  // K-row permutation: output row i(=q16) of sub-tile s reads kv row 8*(i>>2)+(i&3)+4s
  const int rowoff = ((q16 >> 2) << 3) + (q16 & 3);
  const int koff0 = SWZK(rowoff * 128 + g * 16);
  const int koff1 = SWZK(rowoff * 128 + 64 + g * 16);
  const int koff2 = SWZK((rowoff + 4) * 128 + g * 16);
  const int koff3 = SWZK((rowoff + 4) * 128 + 64 + g * 16);
  const int voff0 = 4096 + (q16 +  0) * 64 + g * 16;
  const int voff1 = 4096 + (q16 + 16) * 64 + g * 16;
  const int voff2 = 4096 + (q16 + 32) * 64 + g * 16;
  const int voff3 = 4096 + (q16 + 48) * 64 + g * 16;

  f32x4 acc0 = {0,0,0,0}, acc1 = {0,0,0,0}, acc2 = {0,0,0,0}, acc3 = {0,0,0,0};
  float m = CONST_M;
  float l = 0.0f;

  if (b0i < b1i) {
    STAGE_LOAD(base + b0i * 32);
    STAGE_WRITE(0);
    __syncthreads();
    int cur = 0;
    for (int b = b0i; b < b1i; ++b) {
      const bool more = (b + 1 < b1i);
      if (more) STAGE_LOAD(base + (b + 1) * 32);
      STEP(cur, base + b * 32);
      if (more) STAGE_WRITE(cur ^ 1);
      __syncthreads();
      cur ^= 1;
    }
  }

  // cross-g reduce of l (m already uniform across g)
  l += __shfl_xor(l, 16);
  l += __shfl_xor(l, 32);

  // write bf16 partials (nt: consumer is merge on another XCD)
  const int row = q0w + q16;
  unsigned short* pr = pacc + ((size_t)row * NC + c) * 64;
  u16x4 h0, h1, h2, h3;
#pragma unroll
  for (int r = 0; r < 4; ++r) {
    h0[r] = f2bf(acc0[r]); h1[r] = f2bf(acc1[r]);
    h2[r] = f2bf(acc2[r]); h3[r] = f2bf(acc3[r]);
  }
  __builtin_nontemporal_store(h0, (u16x4*)(pr + 0  + g * 4));
  __builtin_nontemporal_store(h1, (u16x4*)(pr + 16 + g * 4));
  __builtin_nontemporal_store(h2, (u16x4*)(pr + 32 + g * 4));
  __builtin_nontemporal_store(h3, (u16x4*)(pr + 48 + g * 4));
  if (g == 0) {
    f32x2 v; v[0] = m; v[1] = l;
    __builtin_nontemporal_store(v, (f32x2*)(pml + ((size_t)row * NC + c) * 2));
  }
}

// ---- merge NC bf16 chunk-partials per q-row ----
__global__ __launch_bounds__(256) void merge_kernel(
    const unsigned short* __restrict__ pacc, const float* __restrict__ pml,
    float* __restrict__ out)
{
  const int nb8 = gridDim.x >> 3;
  const int bq = ((gridDim.x & 7) == 0) ? ((blockIdx.x & 7) * nb8 + (blockIdx.x >> 3))
                                        : blockIdx.x;
  const int q0 = bq * 16;
  const int t = threadIdx.x;
  const int i = t >> 4;
  const int c0 = (t & 15) * 4;
  const int R = q0 + i;

  float mm[NC], ll[NC], sc[NC];
  float mstar = NEG_INF;
#pragma unroll
  for (int cc = 0; cc < NC; ++cc) {
    f32x2 v = *(const f32x2*)(pml + ((size_t)R * NC + cc) * 2);
    mm[cc] = v[0]; ll[cc] = v[1];
    mstar = fmaxf(mstar, v[0]);
  }
  float L = 0.0f;
#pragma unroll
  for (int cc = 0; cc < NC; ++cc) {
    sc[cc] = __builtin_exp2f(mm[cc] - mstar);
    L += sc[cc] * ll[cc];
  }
  float inv = (L > 0.0f) ? 1.0f / L : 0.0f;
  f32x4 num = {0, 0, 0, 0};
#pragma unroll
  for (int cc = 0; cc < NC; ++cc) {
    u16x4 a = *(const u16x4*)&pacc[((size_t)R * NC + cc) * 64 + c0];
    float s = sc[cc];
    num[0] += s * bf2f(a[0]); num[1] += s * bf2f(a[1]);
    num[2] += s * bf2f(a[2]); num[3] += s * bf2f(a[3]);
  }
  f32x4 o;
  o[0] = num[0] * inv; o[1] = num[1] * inv;
  o[2] = num[2] * inv; o[3] = num[3] * inv;
  *(f32x4*)&out[(size_t)R * 64 + c0] = o;
}

extern "C" void kernel_launch(void* const* d_in, const int* in_sizes, int n_in,
                              void* d_out, int out_size, void* d_ws, size_t ws_size,
                              hipStream_t stream) {
  const float* q  = (const float*)d_in[0];
  const float* kv = (const float*)d_in[1];
  const int* qc   = (const int*)d_in[2];
  const int* kvc  = (const int*)d_in[3];
  float* out = (float*)d_out;

  const int C = 64;
  const int n1 = in_sizes[0] / C;   // 8192
  const int n2 = in_sizes[1] / C;   // 8192

  char* ws = (char*)d_ws;
  size_t off = 0;
  unsigned short* kvb = (unsigned short*)(ws + off); off += (size_t)n2 * C * 2;
  unsigned short* kvt = (unsigned short*)(ws + off); off += (size_t)n2 * C * 2;
  unsigned short* qb  = (unsigned short*)(ws + off); off += (size_t)n1 * C * 2;
  int* seg = (int*)(ws + off); off += 4096;
  unsigned short* pacc = (unsigned short*)(ws + off); off += (size_t)n1 * NC * 64 * 2;
  float* pml = (float*)(ws + off);

  prep_kv_kernel<<<n2 / 16, 256, 0, stream>>>(kv, q, kvc, kvb, kvt, qb, seg, n2, n1);
  attn_kernel<<<(n1 / 128) * NC, 512, 0, stream>>>(qb, kvb, kvt, qc, seg, pacc, pml, n2);
  merge_kernel<<<n1 / 16, 256, 0, stream>>>(pacc, pml, out);
}

// Round 27
// 25.039 us; speedup vs baseline: 1.2115x; 1.2115x over previous
//
#include <hip/hip_runtime.h>
#include <hip/hip_bf16.h>

typedef __attribute__((ext_vector_type(8))) short bf16x8;
typedef __attribute__((ext_vector_type(4))) unsigned short u16x4;
typedef __attribute__((ext_vector_type(4))) float f32x4;
typedef __attribute__((ext_vector_type(2))) float f32x2;

#define NEG_INF (-__builtin_inff())
#define QSCALE (0.125f * 1.4426950408889634f)   // 1/sqrt(64) * log2(e); exp2 domain
#define CONST_M 12.0f                            // safe upper bound on exp2-domain scores
#define NC 8
#define NCL2 3

// K-region LDS swizzle: rows of 128B; spread 16B slots by (row&3)|((row>>3)&1)<<2
#define SWZK(a) ((a) ^ ((((((a) >> 7) & 3) | ((((a) >> 10) & 1) << 2)) << 4)))

static __device__ __forceinline__ unsigned short f2bf(float x) {
  union { float f; unsigned u; } v; v.f = x;
  unsigned r = (v.u + 0x7fffu + ((v.u >> 16) & 1u)) >> 16;
  return (unsigned short)r;
}
static __device__ __forceinline__ float bf2f(unsigned short h) {
  union { unsigned u; float f; } v; v.u = ((unsigned)h) << 16;
  return v.f;
}

// ---- prep: per block, 16 KV rows -> bf16 row-major + blocked transpose
// ---- kvt[blk32][64][32], AND 16 Q rows -> bf16 with QSCALE folded; nt stores ----
__global__ __launch_bounds__(256) void prep_kv_kernel(
    const float* __restrict__ kv, const float* __restrict__ qf,
    const int* __restrict__ kvc,
    unsigned short* __restrict__ kvb, unsigned short* __restrict__ kvt,
    unsigned short* __restrict__ qb,
    int* __restrict__ seg, int nkv, int nq) {
  __shared__ unsigned short tile[16][64];
  const int nb8 = gridDim.x >> 3;
  const int bp = ((gridDim.x & 7) == 0) ? ((blockIdx.x & 7) * nb8 + (blockIdx.x >> 3))
                                        : blockIdx.x;
  const int rowbase = bp * 16;
  const int t = threadIdx.x;
  if (t < 16) {
    int i = rowbase + t;
    if (i < nkv) {
      int c = kvc[i];
      int cp = (i == 0) ? -1 : kvc[i - 1];
      if (c != cp) {
        for (int b = cp + 1; b <= c; ++b) seg[b] = i;
        if (i == 0) for (int b = 0; b < c; ++b) seg[8 + b] = 0;
      }
      int cn = (i == nkv - 1) ? 8 : kvc[i + 1];
      if (c != cn) {
        for (int b = c; b < cn; ++b) seg[8 + b] = i + 1;
        if (i == nkv - 1) for (int b = c + 1; b < 8; ++b) seg[b] = nkv;
      }
    }
  }
  const int r = t >> 4;
  const int c = (t & 15) * 4;
  // Q conversion (scale folded; bit-identical to prior in-attn f2bf(x*QSCALE))
  if (rowbase + r < nq) {
    float4 aq = *(const float4*)(qf + (size_t)(rowbase + r) * 64 + c);
    u16x4 q4;
    q4[0] = f2bf(aq.x * QSCALE); q4[1] = f2bf(aq.y * QSCALE);
    q4[2] = f2bf(aq.z * QSCALE); q4[3] = f2bf(aq.w * QSCALE);
    __builtin_nontemporal_store(q4, (u16x4*)(qb + (size_t)(rowbase + r) * 64 + c));
  }
  float4 a = *(const float4*)(kv + (size_t)(rowbase + r) * 64 + c);
  u16x4 v4;
  v4[0] = f2bf(a.x); v4[1] = f2bf(a.y); v4[2] = f2bf(a.z); v4[3] = f2bf(a.w);
  __builtin_nontemporal_store(v4, (u16x4*)(kvb + (size_t)(rowbase + r) * 64 + c));
  *(u16x4*)&tile[r][c] = v4;
  __syncthreads();
  const int d = t & 63;
  const int k0 = (t >> 6) * 4;
  u16x4 wv;
#pragma unroll
  for (int j = 0; j < 4; ++j) wv[j] = tile[k0 + j][d];
  const int blk = rowbase >> 5;
  const int kbase = (rowbase & 31) + k0;
  __builtin_nontemporal_store(wv, (u16x4*)(kvt + (size_t)blk * 2048 + d * 32 + kbase));
}

// issue the global load for a 32-row KV block (each thread one 16B chunk)
#define STAGE_LOAD(kvx)                                                        \
  {                                                                            \
    const int kvL_ = (kvx);                                                    \
    const char* src_ = stK ? ((const char*)kvb + (size_t)kvL_ * 128 + soff)    \
                           : ((const char*)kvt + (((size_t)kvL_) >> 5) * 4096 + soff); \
    sreg = *(const f32x4*)src_;                                                \
  }
#define STAGE_WRITE(BUF) { *(f32x4*)(ldsbuf[BUF] + doff) = sreg; }

// one 32-kv-row step for this wave's 16 queries, K/V fragments read from LDS
#define STEP(BUF, kvx)                                                         \
  {                                                                            \
    const int kv0_ = (kvx);                                                    \
    const char* Lb_ = ldsbuf[BUF];                                             \
    bf16x8 kf0_ = *(const bf16x8*)(Lb_ + koff0);                               \
    bf16x8 kf1_ = *(const bf16x8*)(Lb_ + koff1);                               \
    bf16x8 kf2_ = *(const bf16x8*)(Lb_ + koff2);                               \
    bf16x8 kf3_ = *(const bf16x8*)(Lb_ + koff3);                               \
    bf16x8 vf0_ = *(const bf16x8*)(Lb_ + voff0);                               \
    bf16x8 vf1_ = *(const bf16x8*)(Lb_ + voff1);                               \
    bf16x8 vf2_ = *(const bf16x8*)(Lb_ + voff2);                               \
    bf16x8 vf3_ = *(const bf16x8*)(Lb_ + voff3);                               \
    f32x4 z_ = {0, 0, 0, 0};                                                   \
    __builtin_amdgcn_s_setprio(1);                                             \
    f32x4 sT0 = __builtin_amdgcn_mfma_f32_16x16x32_bf16(kf0_, qf0, z_, 0, 0, 0); \
    sT0 = __builtin_amdgcn_mfma_f32_16x16x32_bf16(kf1_, qf1, sT0, 0, 0, 0);    \
    f32x4 sT1 = __builtin_amdgcn_mfma_f32_16x16x32_bf16(kf2_, qf0, z_, 0, 0, 0); \
    sT1 = __builtin_amdgcn_mfma_f32_16x16x32_bf16(kf3_, qf1, sT1, 0, 0, 0);    \
    __builtin_amdgcn_s_setprio(0);                                             \
    float v_[8];                                                               \
    const bool full_ = uniformb && (kv0_ >= kv_lo) && (kv0_ + 32 <= kv_hi);    \
    if (full_) {                                                               \
      _Pragma("unroll") for (int r = 0; r < 4; ++r) {                          \
        v_[r] = sT0[r]; v_[4 + r] = sT1[r];                                    \
      }                                                                        \
    } else {                                                                   \
      const int kb0_ = kv0_ + g8;                                              \
      _Pragma("unroll") for (int r = 0; r < 4; ++r) {                          \
        v_[r]     = (kb0_ + r     >= lo_q && kb0_ + r     < hi_q) ? sT0[r] : NEG_INF; \
        v_[4 + r] = (kb0_ + r + 4 >= lo_q && kb0_ + r + 4 < hi_q) ? sT1[r] : NEG_INF; \
      }                                                                        \
    }                                                                          \
    float t_ = fmaxf(fmaxf(fmaxf(v_[0], v_[1]), fmaxf(v_[2], v_[3])),          \
                     fmaxf(fmaxf(v_[4], v_[5]), fmaxf(v_[6], v_[7])));         \
    if (__builtin_expect(__any(t_ > m), 0)) {                                  \
      float tt_ = fmaxf(t_, __shfl_xor(t_, 16));                               \
      tt_ = fmaxf(tt_, __shfl_xor(tt_, 32));                                   \
      float mn_ = fmaxf(m, tt_);                                               \
      float f_ = __builtin_exp2f(m - mn_);                                     \
      l *= f_;                                                                 \
      _Pragma("unroll") for (int r = 0; r < 4; ++r) {                          \
        acc0[r] *= f_; acc1[r] *= f_; acc2[r] *= f_; acc3[r] *= f_;            \
      }                                                                        \
      m = mn_;                                                                 \
    }                                                                          \
    float e_[8];                                                               \
    _Pragma("unroll") for (int i = 0; i < 8; ++i)                              \
      e_[i] = __builtin_exp2f(v_[i] - m);                                      \
    l += (((e_[0] + e_[1]) + (e_[2] + e_[3])) +                                \
          ((e_[4] + e_[5]) + (e_[6] + e_[7])));                                \
    bf16x8 pa_;                                                                \
    _Pragma("unroll") for (int j = 0; j < 8; ++j) pa_[j] = (short)f2bf(e_[j]); \
    __builtin_amdgcn_s_setprio(1);                                             \
    acc0 = __builtin_amdgcn_mfma_f32_16x16x32_bf16(vf0_, pa_, acc0, 0, 0, 0);  \
    acc1 = __builtin_amdgcn_mfma_f32_16x16x32_bf16(vf1_, pa_, acc1, 0, 0, 0);  \
    acc2 = __builtin_amdgcn_mfma_f32_16x16x32_bf16(vf2_, pa_, acc2, 0, 0, 0);  \
    acc3 = __builtin_amdgcn_mfma_f32_16x16x32_bf16(vf3_, pa_, acc3, 0, 0, 0);  \
    __builtin_amdgcn_s_setprio(0);                                             \
  }

// ---- attn partials: 512-thread block = 128 queries (8 waves x 16q), KV block
// ---- staged ONCE into LDS, shared by all 8 waves; KV split NC across blocks;
// ---- Q read as pre-scaled bf16 (2 b128 loads); bf16+nt partials ----
__global__ __launch_bounds__(512, 4) void attn_kernel(
    const unsigned short* __restrict__ qb,   // [n1][64] bf16 (pre-scaled)
    const unsigned short* __restrict__ kvb,  // [n2][64] bf16
    const unsigned short* __restrict__ kvt,  // [n2/32][64][32] bf16
    const int* __restrict__ qc,
    const int* __restrict__ seg,
    unsigned short* __restrict__ pacc,       // [n1][NC][64] bf16
    float* __restrict__ pml,                 // [n1][NC] {m,l} pairs (flat f32)
    int n2)
{
  __shared__ __attribute__((aligned(16))) char ldsbuf[2][8192];  // [K 4KB swz | V 4KB]

  const int per8 = gridDim.x >> 3;
  const int ii = ((gridDim.x & 7) == 0) ? ((blockIdx.x & 7) * per8 + (blockIdx.x >> 3))
                                        : blockIdx.x;
  const int qt = ii >> NCL2;                // 128-query tile
  const int c  = ii & (NC - 1);             // kv chunk
  const int qbase = qt << 7;

  const int tid = threadIdx.x;
  const int w = tid >> 6;                   // 0..7
  const int lane = tid & 63;
  const int q16 = lane & 15;
  const int g = lane >> 4;
  const int g8 = g * 8;
  const int q0w = qbase + w * 16;

  // staging assignment: threads 0-255 stage K rows, 256-511 stage V (kvt block)
  const bool stK = tid < 256;
  const int soff = (tid & 255) * 16;
  const int doff = stK ? SWZK(soff) : 4096 + soff;
  f32x4 sreg;

  const int myb = qc[q0w + q16];
  const int lo_q = seg[myb];
  const int hi_q = seg[8 + myb];
  const int bfirst = qc[qbase];
  const int blast  = qc[qbase + 127];
  const int kv_lo  = seg[bfirst];
  const int kv_hi  = seg[8 + blast];
  const bool uniformb = (bfirst == blast);

  // Q B-fragments (pre-scaled bf16): B[feat=8g+j][q=q16]
  const unsigned short* qr = qb + (size_t)(q0w + q16) * 64 + g8;
  bf16x8 qf0 = *(const bf16x8*)(qr);
  bf16x8 qf1 = *(const bf16x8*)(qr + 32);

  const int base = kv_lo & ~31;
  const int nblk = (kv_hi - base + 31) >> 5;
  const int b0i = (nblk * c) >> NCL2;
  const int b1i = (nblk * (c + 1)) >> NCL2;

  // K-row permutation: output row i(=q16) of sub-tile s reads kv row 8*(i>>2)+(i&3)+4s
  const int rowoff = ((q16 >> 2) << 3) + (q16 & 3);
  const int koff0 = SWZK(rowoff * 128 + g * 16);
  const int koff1 = SWZK(rowoff * 128 + 64 + g * 16);
  const int koff2 = SWZK((rowoff + 4) * 128 + g * 16);
  const int koff3 = SWZK((rowoff + 4) * 128 + 64 + g * 16);
  const int voff0 = 4096 + (q16 +  0) * 64 + g * 16;
  const int voff1 = 4096 + (q16 + 16) * 64 + g * 16;
  const int voff2 = 4096 + (q16 + 32) * 64 + g * 16;
  const int voff3 = 4096 + (q16 + 48) * 64 + g * 16;

  f32x4 acc0 = {0,0,0,0}, acc1 = {0,0,0,0}, acc2 = {0,0,0,0}, acc3 = {0,0,0,0};
  float m = CONST_M;
  float l = 0.0f;

  if (b0i < b1i) {
    STAGE_LOAD(base + b0i * 32);
    STAGE_WRITE(0);
    __syncthreads();
    int cur = 0;
    for (int b = b0i; b < b1i; ++b) {
      const bool more = (b + 1 < b1i);
      if (more) STAGE_LOAD(base + (b + 1) * 32);
      STEP(cur, base + b * 32);
      if (more) STAGE_WRITE(cur ^ 1);
      __syncthreads();
      cur ^= 1;
    }
  }

  // cross-g reduce of l (m already uniform across g)
  l += __shfl_xor(l, 16);
  l += __shfl_xor(l, 32);

  // write bf16 partials (nt: consumer is merge on another XCD)
  const int row = q0w + q16;
  unsigned short* pr = pacc + ((size_t)row * NC + c) * 64;
  u16x4 h0, h1, h2, h3;
#pragma unroll
  for (int r = 0; r < 4; ++r) {
    h0[r] = f2bf(acc0[r]); h1[r] = f2bf(acc1[r]);
    h2[r] = f2bf(acc2[r]); h3[r] = f2bf(acc3[r]);
  }
  __builtin_nontemporal_store(h0, (u16x4*)(pr + 0  + g * 4));
  __builtin_nontemporal_store(h1, (u16x4*)(pr + 16 + g * 4));
  __builtin_nontemporal_store(h2, (u16x4*)(pr + 32 + g * 4));
  __builtin_nontemporal_store(h3, (u16x4*)(pr + 48 + g * 4));
  if (g == 0) {
    f32x2 v; v[0] = m; v[1] = l;
    __builtin_nontemporal_store(v, (f32x2*)(pml + ((size_t)row * NC + c) * 2));
  }
}

// ---- merge NC bf16 chunk-partials per q-row ----
__global__ __launch_bounds__(256) void merge_kernel(
    const unsigned short* __restrict__ pacc, const float* __restrict__ pml,
    float* __restrict__ out)
{
  const int nb8 = gridDim.x >> 3;
  const int bq = ((gridDim.x & 7) == 0) ? ((blockIdx.x & 7) * nb8 + (blockIdx.x >> 3))
                                        : blockIdx.x;
  const int q0 = bq * 16;
  const int t = threadIdx.x;
  const int i = t >> 4;
  const int c0 = (t & 15) * 4;
  const int R = q0 + i;

  float mm[NC], ll[NC], sc[NC];
  float mstar = NEG_INF;
#pragma unroll
  for (int cc = 0; cc < NC; ++cc) {
    f32x2 v = *(const f32x2*)(pml + ((size_t)R * NC + cc) * 2);
    mm[cc] = v[0]; ll[cc] = v[1];
    mstar = fmaxf(mstar, v[0]);
  }
  float L = 0.0f;
#pragma unroll
  for (int cc = 0; cc < NC; ++cc) {
    sc[cc] = __builtin_exp2f(mm[cc] - mstar);
    L += sc[cc] * ll[cc];
  }
  float inv = (L > 0.0f) ? 1.0f / L : 0.0f;
  f32x4 num = {0, 0, 0, 0};
#pragma unroll
  for (int cc = 0; cc < NC; ++cc) {
    u16x4 a = *(const u16x4*)&pacc[((size_t)R * NC + cc) * 64 + c0];
    float s = sc[cc];
    num[0] += s * bf2f(a[0]); num[1] += s * bf2f(a[1]);
    num[2] += s * bf2f(a[2]); num[3] += s * bf2f(a[3]);
  }
  f32x4 o;
  o[0] = num[0] * inv; o[1] = num[1] * inv;
  o[2] = num[2] * inv; o[3] = num[3] * inv;
  *(f32x4*)&out[(size_t)R * 64 + c0] = o;
}

extern "C" void kernel_launch(void* const* d_in, const int* in_sizes, int n_in,
                              void* d_out, int out_size, void* d_ws, size_t ws_size,
                              hipStream_t stream) {
  const float* q  = (const float*)d_in[0];
  const float* kv = (const float*)d_in[1];
  const int* qc   = (const int*)d_in[2];
  const int* kvc  = (const int*)d_in[3];
  float* out = (float*)d_out;

  const int C = 64;
  const int n1 = in_sizes[0] / C;   // 8192
  const int n2 = in_sizes[1] / C;   // 8192

  char* ws = (char*)d_ws;
  size_t off = 0;
  unsigned short* kvb = (unsigned short*)(ws + off); off += (size_t)n2 * C * 2;
  unsigned short* kvt = (unsigned short*)(ws + off); off += (size_t)n2 * C * 2;
  unsigned short* qb  = (unsigned short*)(ws + off); off += (size_t)n1 * C * 2;
  int* seg = (int*)(ws + off); off += 4096;
  unsigned short* pacc = (unsigned short*)(ws + off); off += (size_t)n1 * NC * 64 * 2;
  float* pml = (float*)(ws + off);

  prep_kv_kernel<<<n2 / 16, 256, 0, stream>>>(kv, q, kvc, kvb, kvt, qb, seg, n2, n1);
  attn_kernel<<<(n1 / 128) * NC, 512, 0, stream>>>(qb, kvb, kvt, qc, seg, pacc, pml, n2);
  merge_kernel<<<n1 / 16, 256, 0, stream>>>(pacc, pml, out);
}